// Round 10
// baseline (327.408 us; speedup 1.0000x reference)
//
#include <hip/hip_runtime.h>
#include <hip/hip_bf16.h>
#include <hip/hip_fp16.h>

#define N_NODES 100000
#define N_EDGES 1600000
#define N_GRAPHS 64

#define NB_BKT 256      // node buckets for CSR build
#define NPBKT 391       // nodes per bucket (255*391=99705, last bucket 295)
#define EPB 4096        // edges per bin block
#define NBLK_FEAT ((N_NODES + 255) / 256)            // 391
#define NBLK_BIN ((N_EDGES + EPB - 1) / EPB)         // 391
#define BKT_CAP 7168    // per-bucket rec capacity: mean 6256, sigma 79 -> +11.5 sigma

// ---------------- f16 helpers ----------------

__device__ __forceinline__ __half2 u2h(unsigned int u) {
    return __builtin_bit_cast(__half2, u);
}
__device__ __forceinline__ unsigned int h2u(__half2 h) {
    return __builtin_bit_cast(unsigned int, h);
}
__device__ __forceinline__ float2 u2f2(unsigned int u) {
    return __half22float2(u2h(u));
}
__device__ __forceinline__ unsigned int packh2(float a, float b) {
    return __builtin_bit_cast(unsigned int, __float22half2_rn(make_float2(a, b)));
}

// ---------------- prep: feat->f16 rows (blocks [0,391)) + edge binning (blocks [391,782)) ----

__global__ __launch_bounds__(256) void prep(const float* __restrict__ feat,
                                            const int* __restrict__ dst,
                                            const int* __restrict__ src,
                                            uint4* __restrict__ feat16,
                                            int* __restrict__ gcur,
                                            uint2* __restrict__ rec, int n, int E) {
    __shared__ int cnt[NB_BKT];
    __shared__ int lbase[NB_BKT];
    __shared__ int gofs[NB_BKT];
    __shared__ uint2 stage[EPB];  // 32 KB
    int t = threadIdx.x;

    if ((int)blockIdx.x < NBLK_FEAT) {
        __shared__ float sf[256 * 6];
        int b0 = blockIdx.x * 256;
        int c = min(256, n - b0) * 6;
        for (int i = t; i < c; i += 256) sf[i] = feat[(size_t)b0 * 6 + i];
        __syncthreads();
        int v = b0 + t;
        if (v < n) {
            const float* f = sf + t * 6;
            uint4 r;
            r.x = packh2(f[0], f[1]);
            r.y = packh2(f[2], f[3]);
            r.z = packh2(f[4], f[5]);
            r.w = 0u;
            feat16[v] = r;
        }
        return;
    }

    int e0 = (blockIdx.x - NBLK_FEAT) * EPB;
    cnt[t] = 0;
    __syncthreads();
    int myb[16], mypos[16];
    unsigned myd[16], mys[16];
#pragma unroll
    for (int k = 0; k < 16; ++k) {
        int e = e0 + k * 256 + t;
        if (e < E) {
            unsigned d = (unsigned)dst[e];
            int b = (int)(d / (unsigned)NPBKT);
            myd[k] = d;
            mys[k] = (unsigned)src[e];
            myb[k] = b;
            mypos[k] = atomicAdd(&cnt[b], 1);
        } else {
            myb[k] = -1;
        }
    }
    __syncthreads();
    int c = cnt[t];
    int res = (c > 0) ? atomicAdd(&gcur[t], c) : 0;  // reserve range in bucket t
    lbase[t] = c;
    __syncthreads();
    for (int o = 1; o < 256; o <<= 1) {
        int a = (t >= o) ? lbase[t - o] : 0;
        __syncthreads();
        lbase[t] += a;
        __syncthreads();
    }
    lbase[t] -= c;
    gofs[t] = res;
    __syncthreads();
#pragma unroll
    for (int k = 0; k < 16; ++k)
        if (myb[k] >= 0) stage[lbase[myb[k]] + mypos[k]] = make_uint2(myd[k], mys[k]);
    __syncthreads();
    int total = min(EPB, E - e0);
    for (int i = t; i < total; i += 256) {
        int lo = 0, hi = NB_BKT - 1;
        while (lo < hi) {
            int m = (lo + hi + 1) >> 1;
            if (lbase[m] <= i) lo = m; else hi = m - 1;
        }
        rec[(size_t)lo * BKT_CAP + gofs[lo] + (i - lbase[lo])] = stage[i];
    }
}

// ---------------- fill_bucket: one workgroup per bucket ----------------

__global__ __launch_bounds__(256) void fill_bucket(const uint2* __restrict__ rec,
                                                   const int* __restrict__ gcur,
                                                   int* __restrict__ rp,
                                                   int* __restrict__ col, int n) {
    __shared__ int sdeg[512];
    __shared__ int lcur[512];
    __shared__ int sg[256];
    __shared__ int lcol[8192];
    int p = blockIdx.x, t = threadIdx.x;
    int nbase = p * NPBKT;
    int nn = min(NPBKT, n - nbase);
    int g = gcur[t];
    sg[t] = g;
    __syncthreads();
    for (int o = 1; o < 256; o <<= 1) {
        int a = (t >= o) ? sg[t - o] : 0;
        __syncthreads();
        sg[t] += a;
        __syncthreads();
    }
    int ex = sg[t] - g;
    __syncthreads();
    sg[t] = ex;
    __syncthreads();
    int cbase = sg[p];
    int cnt = gcur[p];
    sdeg[t] = 0;
    sdeg[t + 256] = 0;
    __syncthreads();
    const uint2* r = rec + (size_t)p * BKT_CAP;
    for (int i = t; i < cnt; i += 256) atomicAdd(&sdeg[r[i].x - (unsigned)nbase], 1);
    __syncthreads();
    int c0 = sdeg[t], c1 = sdeg[t + 256];
    for (int o = 1; o < 512; o <<= 1) {
        int a = (t >= o) ? sdeg[t - o] : 0;
        int b = (t + 256 >= o) ? sdeg[t + 256 - o] : 0;
        __syncthreads();
        sdeg[t] += a;
        sdeg[t + 256] += b;
        __syncthreads();
    }
    int ex0 = sdeg[t] - c0, ex1 = sdeg[t + 256] - c1;
    lcur[t] = ex0;
    lcur[t + 256] = ex1;
    if (t < nn) rp[nbase + t] = cbase + ex0;
    if (t + 256 < nn) rp[nbase + t + 256] = cbase + ex1;
    if (p == NB_BKT - 1 && t == 0) rp[n] = cbase + cnt;
    __syncthreads();
    for (int i = t; i < cnt; i += 256) {
        uint2 e = r[i];
        int slot = atomicAdd(&lcur[e.x - (unsigned)nbase], 1);
        lcol[slot] = (int)e.y;
    }
    __syncthreads();
    for (int i = t; i < cnt; i += 256) col[cbase + i] = lcol[i];
}

// ---------------- Split-gather fused layer ----------------
// 512 threads: two 256-thread halves each gather alternating 8-edge batches of the
// SAME NPB nodes (doubles resident gather waves; per-wave pattern = proven r6 8-deep).
// Partial sums merge via f16-packed LDS; GEMM in fp32 with fp32 weights.

template <int DIN, int DOUT>
__global__ __launch_bounds__(512, 8) void sage_split(const uint4* __restrict__ hin,
                                                     const int* __restrict__ rp,
                                                     const int* __restrict__ col,
                                                     const float* __restrict__ W,
                                                     const float* __restrict__ bias,
                                                     unsigned int* __restrict__ hout,
                                                     int real_din, int n) {
    constexpr int WPN = DIN / 8;       // lanes per node per half
    constexpr int NPB = 512 / (2 * WPN);
    constexpr int TPN2 = 2 * WPN;      // threads per node in GEMM phase
    constexpr int OPT = DOUT / TPN2;
    __shared__ float sW[DIN * DOUT];
    __shared__ float sB[DOUT];
    __shared__ unsigned sH[2][NPB][DIN / 2];
    __shared__ float sInv[NPB];

    int tid = threadIdx.x;
    for (int i = tid; i < DIN * DOUT; i += 512) sW[i] = (i < real_din * DOUT) ? W[i] : 0.f;
    if (tid < DOUT) sB[tid] = bias[tid];

    int half = tid >> 8;
    int t256 = tid & 255;
    int sub = t256 / WPN;
    int t = t256 % WPN;
    int v = blockIdx.x * NPB + sub;

    if (v < n) {
        int r0 = rp[v], r1 = rp[v + 1];
        uint4 ws = make_uint4(0u, 0u, 0u, 0u);
        if (half == 0) ws = hin[v * WPN + t];  // self row, issued early
        const __half2 z = __float2half2_rn(0.f);
        __half2 acc[4][4];
#pragma unroll
        for (int s = 0; s < 4; ++s)
#pragma unroll
            for (int q = 0; q < 4; ++q) acc[s][q] = z;

        for (int j = r0 + 8 * half; j < r1; j += 16) {
            int m = r1 - j;
            if (m >= 8) {
                uint4 w[8];
#pragma unroll
                for (int k = 0; k < 8; ++k) w[k] = hin[col[j + k] * WPN + t];
#pragma unroll
                for (int k = 0; k < 8; ++k) {
                    __half2* a = acc[k & 3];
                    a[0] = __hadd2(a[0], u2h(w[k].x));
                    a[1] = __hadd2(a[1], u2h(w[k].y));
                    a[2] = __hadd2(a[2], u2h(w[k].z));
                    a[3] = __hadd2(a[3], u2h(w[k].w));
                }
            } else {
                for (int k = 0; k < m; ++k) {
                    uint4 w = hin[col[j + k] * WPN + t];
                    __half2* a = acc[k & 3];
                    a[0] = __hadd2(a[0], u2h(w.x));
                    a[1] = __hadd2(a[1], u2h(w.y));
                    a[2] = __hadd2(a[2], u2h(w.z));
                    a[3] = __hadd2(a[3], u2h(w.w));
                }
            }
        }
        __half2 a0[4];
#pragma unroll
        for (int q = 0; q < 4; ++q)
            a0[q] = __hadd2(__hadd2(acc[0][q], acc[1][q]), __hadd2(acc[2][q], acc[3][q]));
        if (half == 0) {
            unsigned swd[4] = {ws.x, ws.y, ws.z, ws.w};
#pragma unroll
            for (int q = 0; q < 4; ++q) a0[q] = __hadd2(a0[q], u2h(swd[q]));
            if (t == 0) sInv[sub] = 1.0f / (float)(r1 - r0 + 1);
        }
#pragma unroll
        for (int q = 0; q < 4; ++q) sH[half][sub][t * 4 + q] = h2u(a0[q]);
    }
    __syncthreads();

    int g_sub = tid / TPN2;
    int g_t = tid % TPN2;
    int gv = blockIdx.x * NPB + g_sub;
    if (gv < n) {
        float inv = sInv[g_sub];
        int o0 = g_t * OPT;
        float accO[OPT];
#pragma unroll
        for (int i = 0; i < OPT; ++i) accO[i] = sB[o0 + i];
#pragma unroll 4
        for (int kp = 0; kp < DIN / 2; ++kp) {
            float2 f0 = u2f2(sH[0][g_sub][kp]);
            float2 f1 = u2f2(sH[1][g_sub][kp]);
            float hx = (f0.x + f1.x) * inv;
            float hy = (f0.y + f1.y) * inv;
            const float* w0 = sW + (2 * kp) * DOUT + o0;
            const float* w1 = sW + (2 * kp + 1) * DOUT + o0;
#pragma unroll
            for (int i = 0; i < OPT; ++i) accO[i] += hx * w0[i] + hy * w1[i];
        }
        unsigned wds[OPT / 2];
#pragma unroll
        for (int i = 0; i < OPT; i += 2)
            wds[i / 2] = packh2(fmaxf(accO[i], 0.f), fmaxf(accO[i + 1], 0.f));
        unsigned* op = hout + gv * (DOUT / 2) + o0 / 2;
        if constexpr (OPT / 2 == 4) {
            *reinterpret_cast<uint4*>(op) = make_uint4(wds[0], wds[1], wds[2], wds[3]);
        } else if constexpr (OPT / 2 == 2) {
            *reinterpret_cast<uint2*>(op) = make_uint2(wds[0], wds[1]);
        } else {
            *op = wds[0];
        }
    }
}

// ---------------- Pooling: per-graph mean, f16 input ----------------

__device__ __forceinline__ int lower_bound_i(const int* __restrict__ a, int n, int key) {
    int lo = 0, hi = n;
    while (lo < hi) {
        int m = (lo + hi) >> 1;
        if (a[m] < key) lo = m + 1; else hi = m;
    }
    return lo;
}

__global__ __launch_bounds__(256) void pool_f16(const unsigned int* __restrict__ h32,
                                                const int* __restrict__ gids,
                                                float* __restrict__ out, int n) {
    int bx = blockIdx.x;
    int g = bx >> 3, s = bx & 7;
    int start = lower_bound_i(gids, n, g);
    int end = lower_bound_i(gids, n, g + 1);
    int len = end - start;
    float inv = 1.0f / (float)(len > 0 ? len : 1);
    int chunk = (len + 7) / 8;
    int s0 = start + s * chunk;
    int s1 = min(s0 + chunk, end);
    int t = threadIdx.x;
    int d = t & 31, j = t >> 5;
    float a0 = 0.f, a1 = 0.f;
    for (int i = s0 + j; i < s1; i += 8) {
        float2 f = u2f2(h32[(size_t)i * 32 + d]);
        a0 += f.x;
        a1 += f.y;
    }
    __shared__ float red[8][32][2];
    red[j][d][0] = a0;
    red[j][d][1] = a1;
    __syncthreads();
    if (t < 64) {
        int dd = t & 31, e = t >> 5;
        float tot = 0.f;
#pragma unroll
        for (int k = 0; k < 8; ++k) tot += red[k][dd][e];
        atomicAdd(&out[g * 64 + 2 * dd + e], tot * inv);
    }
}

// ---------------- launch ----------------

extern "C" void kernel_launch(void* const* d_in, const int* in_sizes, int n_in,
                              void* d_out, int out_size, void* d_ws, size_t ws_size,
                              hipStream_t stream) {
    const int N = N_NODES, E = N_EDGES;
    const float* feat = (const float*)d_in[0];
    const int* src = (const int*)d_in[1];
    const int* dst = (const int*)d_in[2];
    const int* gids = (const int*)d_in[3];
    const float* W1 = (const float*)d_in[4];
    const float* b1 = (const float*)d_in[5];
    const float* W2 = (const float*)d_in[6];
    const float* b2 = (const float*)d_in[7];
    const float* W3 = (const float*)d_in[8];
    const float* b3 = (const float*)d_in[9];
    const float* W4 = (const float*)d_in[10];
    const float* b4 = (const float*)d_in[11];
    float* out = (float*)d_out;

    // workspace layout
    int* rp = (int*)d_ws;                       // N+1
    int* gcur = rp + (N + 1);                   // 256 bucket cursors
    int* col = gcur + 256;                      // E
    size_t off = (size_t)((char*)(col + E) - (char*)d_ws);
    off = (off + 255) & ~(size_t)255;
    unsigned int* h1 = (unsigned int*)((char*)d_ws + off);   // f16 N*16 (N*8 words)
    unsigned int* h2 = h1 + (size_t)N * 8;                   // f16 N*32 (N*16 words)
    unsigned int* h3 = h2 + (size_t)N * 16;                  // f16 N*64 (N*32 words)
    unsigned int* h4 = h3 + (size_t)N * 32;                  // f16 N*64 (N*32 words)
    uint4* feat16 = (uint4*)(h4 + (size_t)N * 32);           // f16 N*8 padded rows (1.6MB)
    // rec: 256*BKT_CAP uint2 = 14.7MB, aliases h3 + start of h4 (dead until layers 3/4)
    uint2* rec = (uint2*)h3;

    hipMemsetAsync(out, 0, (size_t)N_GRAPHS * 64 * sizeof(float), stream);
    hipMemsetAsync(gcur, 0, 256 * sizeof(int), stream);

    prep<<<NBLK_FEAT + NBLK_BIN, 256, 0, stream>>>(feat, dst, src, feat16, gcur, rec, N, E);
    fill_bucket<<<NB_BKT, 256, 0, stream>>>(rec, gcur, rp, col, N);

    // layer1: DIN=8 (6 real) WPN=1 NPB=256
    sage_split<8, 16><<<(N + 255) / 256, 512, 0, stream>>>(
        feat16, rp, col, W1, b1, h1, 6, N);
    // layer2: DIN=16 WPN=2 NPB=128
    sage_split<16, 32><<<(N + 127) / 128, 512, 0, stream>>>(
        (const uint4*)h1, rp, col, W2, b2, h2, 16, N);
    // layer3: DIN=32 WPN=4 NPB=64
    sage_split<32, 64><<<(N + 63) / 64, 512, 0, stream>>>(
        (const uint4*)h2, rp, col, W3, b3, h3, 32, N);
    // layer4: DIN=64 WPN=8 NPB=32
    sage_split<64, 64><<<(N + 31) / 32, 512, 0, stream>>>(
        (const uint4*)h3, rp, col, W4, b4, h4, 64, N);

    pool_f16<<<N_GRAPHS * 8, 256, 0, stream>>>(h4, gids, out, N);
}

// Round 11
// 185.687 us; speedup vs baseline: 1.7632x; 1.7632x over previous
//
#include <hip/hip_runtime.h>
#include <hip/hip_bf16.h>
#include <hip/hip_fp16.h>

#define N_NODES 100000
#define N_EDGES 1600000
#define N_GRAPHS 64

#define NB_BKT 256      // node buckets for CSR build
#define NPBKT 391       // nodes per bucket (255*391=99705, last bucket 295)
#define EPB 4096        // edges per bin block
#define NBLK_FEAT ((N_NODES + 255) / 256)            // 391
#define NBLK_BIN ((N_EDGES + EPB - 1) / EPB)         // 391
#define BKT_CAP 7168    // per-bucket rec capacity: mean 6256, sigma 79 -> +11.5 sigma

// ---------------- f16 helpers ----------------

__device__ __forceinline__ __half2 u2h(unsigned int u) {
    return __builtin_bit_cast(__half2, u);
}
__device__ __forceinline__ float2 u2f2(unsigned int u) {
    return __half22float2(u2h(u));
}
__device__ __forceinline__ unsigned int packh2(float a, float b) {
    return __builtin_bit_cast(unsigned int, __float22half2_rn(make_float2(a, b)));
}

// ---------------- prep: feat->f16 rows (blocks [0,391)) + edge binning (blocks [391,782)) ----

__global__ __launch_bounds__(256) void prep(const float* __restrict__ feat,
                                            const int* __restrict__ dst,
                                            const int* __restrict__ src,
                                            uint4* __restrict__ feat16,
                                            int* __restrict__ gcur,
                                            uint2* __restrict__ rec, int n, int E) {
    __shared__ int cnt[NB_BKT];
    __shared__ int lbase[NB_BKT];
    __shared__ int gofs[NB_BKT];
    __shared__ uint2 stage[EPB];  // 32 KB
    int t = threadIdx.x;

    if ((int)blockIdx.x < NBLK_FEAT) {
        __shared__ float sf[256 * 6];
        int b0 = blockIdx.x * 256;
        int c = min(256, n - b0) * 6;
        for (int i = t; i < c; i += 256) sf[i] = feat[(size_t)b0 * 6 + i];
        __syncthreads();
        int v = b0 + t;
        if (v < n) {
            const float* f = sf + t * 6;
            uint4 r;
            r.x = packh2(f[0], f[1]);
            r.y = packh2(f[2], f[3]);
            r.z = packh2(f[4], f[5]);
            r.w = 0u;
            feat16[v] = r;
        }
        return;
    }

    int e0 = (blockIdx.x - NBLK_FEAT) * EPB;
    cnt[t] = 0;
    __syncthreads();
    int myb[16], mypos[16];
    unsigned myd[16], mys[16];
#pragma unroll
    for (int k = 0; k < 16; ++k) {
        int e = e0 + k * 256 + t;
        if (e < E) {
            unsigned d = (unsigned)dst[e];
            int b = (int)(d / (unsigned)NPBKT);
            myd[k] = d;
            mys[k] = (unsigned)src[e];
            myb[k] = b;
            mypos[k] = atomicAdd(&cnt[b], 1);
        } else {
            myb[k] = -1;
        }
    }
    __syncthreads();
    int c = cnt[t];
    int res = (c > 0) ? atomicAdd(&gcur[t], c) : 0;  // reserve range in bucket t
    lbase[t] = c;
    __syncthreads();
    for (int o = 1; o < 256; o <<= 1) {
        int a = (t >= o) ? lbase[t - o] : 0;
        __syncthreads();
        lbase[t] += a;
        __syncthreads();
    }
    lbase[t] -= c;
    gofs[t] = res;
    __syncthreads();
#pragma unroll
    for (int k = 0; k < 16; ++k)
        if (myb[k] >= 0) stage[lbase[myb[k]] + mypos[k]] = make_uint2(myd[k], mys[k]);
    __syncthreads();
    int total = min(EPB, E - e0);
    for (int i = t; i < total; i += 256) {
        int lo = 0, hi = NB_BKT - 1;
        while (lo < hi) {
            int m = (lo + hi + 1) >> 1;
            if (lbase[m] <= i) lo = m; else hi = m - 1;
        }
        rec[(size_t)lo * BKT_CAP + gofs[lo] + (i - lbase[lo])] = stage[i];
    }
}

// ---------------- fill_bucket: one workgroup per bucket ----------------

__global__ __launch_bounds__(256) void fill_bucket(const uint2* __restrict__ rec,
                                                   const int* __restrict__ gcur,
                                                   int* __restrict__ rp,
                                                   int* __restrict__ col, int n) {
    __shared__ int sdeg[512];
    __shared__ int lcur[512];
    __shared__ int sg[256];
    __shared__ int lcol[8192];
    int p = blockIdx.x, t = threadIdx.x;
    int nbase = p * NPBKT;
    int nn = min(NPBKT, n - nbase);
    int g = gcur[t];
    sg[t] = g;
    __syncthreads();
    for (int o = 1; o < 256; o <<= 1) {
        int a = (t >= o) ? sg[t - o] : 0;
        __syncthreads();
        sg[t] += a;
        __syncthreads();
    }
    int ex = sg[t] - g;
    __syncthreads();
    sg[t] = ex;
    __syncthreads();
    int cbase = sg[p];
    int cnt = gcur[p];
    sdeg[t] = 0;
    sdeg[t + 256] = 0;
    __syncthreads();
    const uint2* r = rec + (size_t)p * BKT_CAP;
    for (int i = t; i < cnt; i += 256) atomicAdd(&sdeg[r[i].x - (unsigned)nbase], 1);
    __syncthreads();
    int c0 = sdeg[t], c1 = sdeg[t + 256];
    for (int o = 1; o < 512; o <<= 1) {
        int a = (t >= o) ? sdeg[t - o] : 0;
        int b = (t + 256 >= o) ? sdeg[t + 256 - o] : 0;
        __syncthreads();
        sdeg[t] += a;
        sdeg[t + 256] += b;
        __syncthreads();
    }
    int ex0 = sdeg[t] - c0, ex1 = sdeg[t + 256] - c1;
    lcur[t] = ex0;
    lcur[t + 256] = ex1;
    if (t < nn) rp[nbase + t] = cbase + ex0;
    if (t + 256 < nn) rp[nbase + t + 256] = cbase + ex1;
    if (p == NB_BKT - 1 && t == 0) rp[n] = cbase + cnt;
    __syncthreads();
    for (int i = t; i < cnt; i += 256) {
        uint2 e = r[i];
        int slot = atomicAdd(&lcur[e.x - (unsigned)nbase], 1);
        lcol[slot] = (int)e.y;
    }
    __syncthreads();
    for (int i = t; i < cnt; i += 256) col[cbase + i] = lcol[i];
}

// ---------------- Generic fused layer, f16 in/out, 8-deep gather (r6 per-wave code) ----------------
// TB threads; WPN = DIN/8 lanes per node; NPB = TB/WPN nodes share one LDS W tile.
// VGPR ~40 < 64 -> 8 waves/SIMD reachable; layer4 LDS 33.8KB -> 4x512 = 32 waves/CU (cap).

template <int DIN, int DOUT, int TB>
__global__ __launch_bounds__(TB) void sage_f16(const uint4* __restrict__ hin,
                                               const int* __restrict__ rp,
                                               const int* __restrict__ col,
                                               const float* __restrict__ W,
                                               const float* __restrict__ bias,
                                               unsigned int* __restrict__ hout,
                                               int real_din, int n) {
    constexpr int WPN = DIN / 8;
    constexpr int NPB = TB / WPN;
    constexpr int OPT = DOUT / WPN;
    __shared__ float sW[DIN * DOUT];
    __shared__ float sB[DOUT];
    __shared__ float sH[NPB][DIN + 1];

    int tid = threadIdx.x;
    for (int i = tid; i < DIN * DOUT; i += TB) sW[i] = (i < real_din * DOUT) ? W[i] : 0.f;
    if (tid < DOUT) sB[tid] = bias[tid];

    int sub = tid / WPN;
    int t = tid % WPN;
    int v = blockIdx.x * NPB + sub;

    if (v < n) {
        int r0 = rp[v], r1 = rp[v + 1];
        const __half2 z = __float2half2_rn(0.f);
        __half2 acc[4][4];
#pragma unroll
        for (int s = 0; s < 4; ++s)
#pragma unroll
            for (int q = 0; q < 4; ++q) acc[s][q] = z;
        int j = r0;
        for (; j + 8 <= r1; j += 8) {
            uint4 w[8];
#pragma unroll
            for (int k = 0; k < 8; ++k) w[k] = hin[col[j + k] * WPN + t];
#pragma unroll
            for (int k = 0; k < 8; ++k) {
                __half2* a = acc[k & 3];
                a[0] = __hadd2(a[0], u2h(w[k].x));
                a[1] = __hadd2(a[1], u2h(w[k].y));
                a[2] = __hadd2(a[2], u2h(w[k].z));
                a[3] = __hadd2(a[3], u2h(w[k].w));
            }
        }
        for (; j + 4 <= r1; j += 4) {
            uint4 w[4];
#pragma unroll
            for (int k = 0; k < 4; ++k) w[k] = hin[col[j + k] * WPN + t];
#pragma unroll
            for (int k = 0; k < 4; ++k) {
                __half2* a = acc[k];
                a[0] = __hadd2(a[0], u2h(w[k].x));
                a[1] = __hadd2(a[1], u2h(w[k].y));
                a[2] = __hadd2(a[2], u2h(w[k].z));
                a[3] = __hadd2(a[3], u2h(w[k].w));
            }
        }
        for (; j < r1; ++j) {
            uint4 w = hin[col[j] * WPN + t];
            acc[0][0] = __hadd2(acc[0][0], u2h(w.x));
            acc[0][1] = __hadd2(acc[0][1], u2h(w.y));
            acc[0][2] = __hadd2(acc[0][2], u2h(w.z));
            acc[0][3] = __hadd2(acc[0][3], u2h(w.w));
        }
#pragma unroll
        for (int q = 0; q < 4; ++q)
            acc[0][q] = __hadd2(__hadd2(acc[0][q], acc[1][q]),
                                __hadd2(acc[2][q], acc[3][q]));
        uint4 ws = hin[v * WPN + t];
        unsigned swd[4] = {ws.x, ws.y, ws.z, ws.w};
        float inv = 1.0f / (float)(r1 - r0 + 1);
#pragma unroll
        for (int q = 0; q < 4; ++q) {
            float2 f = __half22float2(acc[0][q]);
            float2 s = u2f2(swd[q]);
            sH[sub][t * 8 + 2 * q + 0] = (f.x + s.x) * inv;
            sH[sub][t * 8 + 2 * q + 1] = (f.y + s.y) * inv;
        }
    }
    __syncthreads();
    if (v < n) {
        int o0 = t * OPT;
        float accO[OPT];
#pragma unroll
        for (int i = 0; i < OPT; ++i) accO[i] = sB[o0 + i];
#pragma unroll 4
        for (int k = 0; k < DIN; ++k) {
            float hk = sH[sub][k];
#pragma unroll
            for (int i = 0; i < OPT; ++i) accO[i] += hk * sW[k * DOUT + o0 + i];
        }
        unsigned wds[OPT / 2];
#pragma unroll
        for (int i = 0; i < OPT; i += 2)
            wds[i / 2] = packh2(fmaxf(accO[i], 0.f), fmaxf(accO[i + 1], 0.f));
        unsigned* op = hout + v * (DOUT / 2) + o0 / 2;
        if constexpr (OPT / 2 == 4) {
            *reinterpret_cast<uint4*>(op) = make_uint4(wds[0], wds[1], wds[2], wds[3]);
        } else if constexpr (OPT / 2 == 8) {
            reinterpret_cast<uint4*>(op)[0] = make_uint4(wds[0], wds[1], wds[2], wds[3]);
            reinterpret_cast<uint4*>(op)[1] = make_uint4(wds[4], wds[5], wds[6], wds[7]);
        } else {
            *reinterpret_cast<uint2*>(op) = make_uint2(wds[0], wds[1]);
        }
    }
}

// ---------------- Pooling: per-graph mean, f16 input ----------------

__device__ __forceinline__ int lower_bound_i(const int* __restrict__ a, int n, int key) {
    int lo = 0, hi = n;
    while (lo < hi) {
        int m = (lo + hi) >> 1;
        if (a[m] < key) lo = m + 1; else hi = m;
    }
    return lo;
}

__global__ __launch_bounds__(256) void pool_f16(const unsigned int* __restrict__ h32,
                                                const int* __restrict__ gids,
                                                float* __restrict__ out, int n) {
    int bx = blockIdx.x;
    int g = bx >> 3, s = bx & 7;
    int start = lower_bound_i(gids, n, g);
    int end = lower_bound_i(gids, n, g + 1);
    int len = end - start;
    float inv = 1.0f / (float)(len > 0 ? len : 1);
    int chunk = (len + 7) / 8;
    int s0 = start + s * chunk;
    int s1 = min(s0 + chunk, end);
    int t = threadIdx.x;
    int d = t & 31, j = t >> 5;
    float a0 = 0.f, a1 = 0.f;
    for (int i = s0 + j; i < s1; i += 8) {
        float2 f = u2f2(h32[(size_t)i * 32 + d]);
        a0 += f.x;
        a1 += f.y;
    }
    __shared__ float red[8][32][2];
    red[j][d][0] = a0;
    red[j][d][1] = a1;
    __syncthreads();
    if (t < 64) {
        int dd = t & 31, e = t >> 5;
        float tot = 0.f;
#pragma unroll
        for (int k = 0; k < 8; ++k) tot += red[k][dd][e];
        atomicAdd(&out[g * 64 + 2 * dd + e], tot * inv);
    }
}

// ---------------- launch ----------------

extern "C" void kernel_launch(void* const* d_in, const int* in_sizes, int n_in,
                              void* d_out, int out_size, void* d_ws, size_t ws_size,
                              hipStream_t stream) {
    const int N = N_NODES, E = N_EDGES;
    const float* feat = (const float*)d_in[0];
    const int* src = (const int*)d_in[1];
    const int* dst = (const int*)d_in[2];
    const int* gids = (const int*)d_in[3];
    const float* W1 = (const float*)d_in[4];
    const float* b1 = (const float*)d_in[5];
    const float* W2 = (const float*)d_in[6];
    const float* b2 = (const float*)d_in[7];
    const float* W3 = (const float*)d_in[8];
    const float* b3 = (const float*)d_in[9];
    const float* W4 = (const float*)d_in[10];
    const float* b4 = (const float*)d_in[11];
    float* out = (float*)d_out;

    // workspace layout
    int* rp = (int*)d_ws;                       // N+1
    int* gcur = rp + (N + 1);                   // 256 bucket cursors
    int* col = gcur + 256;                      // E
    size_t off = (size_t)((char*)(col + E) - (char*)d_ws);
    off = (off + 255) & ~(size_t)255;
    unsigned int* h1 = (unsigned int*)((char*)d_ws + off);   // f16 N*16 (N*8 words)
    unsigned int* h2 = h1 + (size_t)N * 8;                   // f16 N*32 (N*16 words)
    unsigned int* h3 = h2 + (size_t)N * 16;                  // f16 N*64 (N*32 words)
    unsigned int* h4 = h3 + (size_t)N * 32;                  // f16 N*64 (N*32 words)
    uint4* feat16 = (uint4*)(h4 + (size_t)N * 32);           // f16 N*8 padded rows (1.6MB)
    // rec: 256*BKT_CAP uint2 = 14.7MB, aliases h3 + start of h4 (dead until layers 3/4)
    uint2* rec = (uint2*)h3;

    hipMemsetAsync(out, 0, (size_t)N_GRAPHS * 64 * sizeof(float), stream);
    hipMemsetAsync(gcur, 0, 256 * sizeof(int), stream);

    prep<<<NBLK_FEAT + NBLK_BIN, 256, 0, stream>>>(feat, dst, src, feat16, gcur, rec, N, E);
    fill_bucket<<<NB_BKT, 256, 0, stream>>>(rec, gcur, rp, col, N);

    // layer1: DIN=8 (6 real) WPN=1 NPB=256, 256 thr (grid 391 keeps all CUs fed)
    sage_f16<8, 16, 256><<<(N + 255) / 256, 256, 0, stream>>>(
        feat16, rp, col, W1, b1, h1, 6, N);
    // layer2: DIN=16 WPN=2 NPB=256, 512 thr
    sage_f16<16, 32, 512><<<(N + 255) / 256, 512, 0, stream>>>(
        (const uint4*)h1, rp, col, W2, b2, h2, 16, N);
    // layer3: DIN=32 WPN=4 NPB=128, 512 thr
    sage_f16<32, 64, 512><<<(N + 127) / 128, 512, 0, stream>>>(
        (const uint4*)h2, rp, col, W3, b3, h3, 32, N);
    // layer4: DIN=64 WPN=8 NPB=64, 512 thr -> LDS 33.8KB, 4 blocks/CU = 32 waves (cap)
    sage_f16<64, 64, 512><<<(N + 63) / 64, 512, 0, stream>>>(
        (const uint4*)h3, rp, col, W4, b4, h4, 64, N);

    pool_f16<<<N_GRAPHS * 8, 256, 0, stream>>>(h4, gids, out, N);
}